// Round 15
// baseline (268.538 us; speedup 1.0000x reference)
//
#include <hip/hip_runtime.h>
#include <math.h>

// Problem constants
#define NB   16
#define CC   256
#define NPTS 16384       // 16*32*32
#define KK   8192
#define Z_OUT 4194304    // NPTS*CC
// d_out: [0,Z_OUT) z_q_out (BCHW), [Z_OUT,Z_OUT+NPTS) idx as float, [Z_OUT+NPTS] loss
// d_out scratch: zb16 = bf16[16384][256] at slot 0, ebf = bf16[8192][256] at slot
// 2,097,152 -- both dead once k_cand completes; k_final overwrites with z_q BCHW.

// ws layout (floats)
#define WS_ENORM 16448
#define WS_CCNT  24640                // int[16384] candidate counts
#define WS_CIDX  41024                // int[16384][64] candidate k lists
#define CAND_CAP 64
#define LCAP     96                   // pre-filter per-n LDS list capacity
#define MARGIN   4.0e-4f              // > 2*eps_bf16 + d-quantum + enorm spread

typedef short v8s __attribute__((ext_vector_type(8)));
typedef float v4f __attribute__((ext_vector_type(4)));

__device__ __forceinline__ void gl_lds16(const void* g, void* l) {
    __builtin_amdgcn_global_load_lds((const __attribute__((address_space(1))) void*)g,
                                     (__attribute__((address_space(3))) void*)l, 16, 0, 0);
}
__device__ __forceinline__ unsigned short f2bf(float f) {   // RNE, finite inputs
    unsigned int u = __float_as_uint(f);
    return (unsigned short)((u + 0x7FFFu + ((u >> 16) & 1u)) >> 16);
}
// monotone float<->uint encoding for atomicMax on floats of any sign
__device__ __forceinline__ unsigned fenc(float f) {
    unsigned u = __float_as_uint(f);
    return (u & 0x80000000u) ? ~u : (u | 0x80000000u);
}
__device__ __forceinline__ float fdec(unsigned m) {
    unsigned u = (m & 0x80000000u) ? (m & 0x7fffffffu) : ~m;
    return __uint_as_float(u);
}

// ---------------- P0 (fused prep): emb->ebf+enorm, z->zb16, zero accumulators -------
// r10-verified fused structure, 3072 blocks x 256 thr. Blocks [0,2048): emb fp32 ->
// ebf bf16 + enorm (4 rows/blk, wave/row); block 0 zeros lossAcc+doneCnt (candCnt
// needs no zeroing: k_cand writes candCnt[n] unconditionally for every n).
// Blocks [2048,3072): z BCHW fp32 -> zb16[n][c] bf16 (grid dim3(16,4,16) linearized
// as b2 = bid-2048: x=b2&15, y=(b2>>4)&3, b=b2>>6).
__global__ void k_prep(const float* __restrict__ z, const float* __restrict__ emb,
                       unsigned short* __restrict__ zb16, unsigned short* __restrict__ ebf,
                       float* __restrict__ enorm, float* __restrict__ lossAcc,
                       int* __restrict__ doneCnt) {
    const int bid = blockIdx.x;
    const int tid = threadIdx.x;
    if (bid < 2048) {
        const int w = tid >> 6, lane = tid & 63;
        const int k = bid * 4 + w;
        const int i = k * CC + lane * 4;
        float4 v = *(const float4*)(emb + i);
        *(ushort4*)(ebf + i) = make_ushort4(f2bf(v.x), f2bf(v.y), f2bf(v.z), f2bf(v.w));
        float s = v.x * v.x + v.y * v.y + v.z * v.z + v.w * v.w;
        for (int off = 32; off > 0; off >>= 1) s += __shfl_down(s, off);
        if (lane == 0) enorm[k] = s;
        if (bid == 0 && tid == 0) { lossAcc[0] = 0.0f; doneCnt[0] = 0; }
    } else {
        __shared__ float ts[64][65];
        const int b2 = bid - 2048;
        const int hw0 = (b2 & 15) * 64, c0 = ((b2 >> 4) & 3) * 64, b = b2 >> 6;
#pragma unroll
        for (int p = 0; p < 4; ++p) {
            int u = p * 256 + tid;
            int ci = u >> 4, j4 = (u & 15) << 2;
            float4 v = *(const float4*)(z + (size_t)b * 262144 + (size_t)(c0 + ci) * 1024 + hw0 + j4);
            ts[ci][j4 + 0] = v.x; ts[ci][j4 + 1] = v.y; ts[ci][j4 + 2] = v.z; ts[ci][j4 + 3] = v.w;
        }
        __syncthreads();
#pragma unroll
        for (int p = 0; p < 4; ++p) {
            int u = p * 256 + tid;
            int hj = u >> 4, i4 = (u & 15) << 2;
            ushort4 o = make_ushort4(f2bf(ts[i4 + 0][hj]), f2bf(ts[i4 + 1][hj]),
                                     f2bf(ts[i4 + 2][hj]), f2bf(ts[i4 + 3][hj]));
            *(ushort4*)(zb16 + (size_t)(b * 1024 + hw0 + hj) * 256 + c0 + i4) = o;
        }
    }
}

// ---------------- Phase 1: single-sweep MFMA candidate generation (r8, UNCHANGED) ---
// r8-verified structure (145 us): 256 blocks x 512 thr (8 waves, 2/SIMD). Block =
// 64 n; B z-tile staged ONCE in LDS (32 KB). Wave w sweeps chunks ci = s*8+w,
// strided L2 window. A depth-3 prefetch ring, B LDS ping-pong. Candidate semantics
// (verified r4-r8/r14): progressive threshold max(shared runmax, own chunk max) -
// MARGIN, (k,dot) -> LDS lists (LCAP=96, the r8-verified capacity), exact final
// filter vs TRUE block-global max, overflow -> full-scan fallback.
// mfma_f32_16x16x32_bf16: A[m=lane&15][c=(lane>>4)*8+j]; B[c][n=lane&15];
// D: col(n)=lane&15, row(k)=(lane>>4)*4+reg.
__global__ __launch_bounds__(512, 2)
void k_cand(const unsigned short* __restrict__ zb16, const unsigned short* __restrict__ ebf,
            int* __restrict__ candCnt, int* __restrict__ candI) {
    __shared__ short    Bs[8][4][512];      // 32 KB  [cchunk][ntile][lane*8]
    __shared__ unsigned runmaxU[64];        // ordered-uint running max per n
    __shared__ int      cnt[64];
    __shared__ int      lstK[64][LCAP];     // 24 KB
    __shared__ float    lstD[64][LCAP];     // 24 KB

    const int tid  = threadIdx.x;
    const int lane = tid & 63;
    const int w    = tid >> 6;              // 0..7
    const int nb   = blockIdx.x << 6;
    const int m16  = lane & 15, q = lane >> 4;

    if (tid < 64) { runmaxU[tid] = 0x007FFFFFu; /* fenc(-inf) */ cnt[tid] = 0; }

    // stage B-tile once: 32 (cc,nt) fragments x 64 lanes x 16B; 4 per wave
#pragma unroll
    for (int p = 0; p < 4; ++p) {
        const int g8 = p * 8 + w;          // 0..31, wave-uniform
        const int cc = g8 >> 2, nt = g8 & 3;
        const unsigned short* g = zb16 + (size_t)(nb + nt * 16 + m16) * 256 + cc * 32 + q * 8;
        gl_lds16(g, &Bs[cc][nt][lane * 8]);
    }

    auto loadA = [&](v8s (&a)[4], int kbr, int cc) {
#pragma unroll
        for (int kt = 0; kt < 4; ++kt)
            a[kt] = *(const v8s*)(ebf + (size_t)(kbr + (kt << 4) + m16) * 256 + (cc << 5) + q * 8);
    };
    auto loadB = [&](v8s (&b)[4], int cc) {
#pragma unroll
        for (int nt = 0; nt < 4; ++nt) b[nt] = *(const v8s*)&Bs[cc][nt][lane * 8];
    };

    v8s aR[4][4];            // A ring (static indices only -- cc fully unrolled)
    v8s bP[4], bN[4];

    // prologue: seed ring with (s=0, cc=0,1,2); registers only, safe pre-barrier
    const int kb0 = w << 6;                // s=0 -> ci=w
    loadA(aR[0], kb0, 0);
    loadA(aR[1], kb0, 1);
    loadA(aR[2], kb0, 2);
    __syncthreads();       // Bs staged + runmaxU/cnt init visible (drains vmcnt once)
    loadB(bP, 0);

#pragma unroll 1
    for (int s = 0; s < 16; ++s) {
        const int kb  = ((s << 3) + w) << 6;           // this wave's chunk (64 k)
        const int kbn = (s < 15) ? kb + 512 : kb;      // next s's chunk (ci+8)
        v4f acc[16];
#pragma unroll
        for (int i = 0; i < 16; ++i) acc[i] = (v4f){0.f, 0.f, 0.f, 0.f};

#pragma unroll
        for (int cc = 0; cc < 8; ++cc) {
            if ((cc & 1) == 0) loadB(bN, (cc + 1) & 7);
            else               loadB(bP, (cc + 1) & 7);
            {
                const int tcc = cc + 3;
                if (tcc < 8) loadA(aR[tcc & 3], kb,  tcc);
                else         loadA(aR[tcc & 3], kbn, tcc - 8);
            }
#pragma unroll
            for (int kt = 0; kt < 4; ++kt)
#pragma unroll
                for (int nt = 0; nt < 4; ++nt)
                    acc[kt * 4 + nt] = __builtin_amdgcn_mfma_f32_16x16x32_bf16(
                        aR[cc & 3][kt], ((cc & 1) ? bN[nt] : bP[nt]),
                        acc[kt * 4 + nt], 0, 0, 0);
        }

        // chunk epilogue: own-chunk max per n-column, merge into shared runmax, push.
        float mx[4];
#pragma unroll
        for (int nt = 0; nt < 4; ++nt) {
            float m = acc[0 * 4 + nt][0];
#pragma unroll
            for (int kt = 0; kt < 4; ++kt)
#pragma unroll
                for (int r = 0; r < 4; ++r) m = fmaxf(m, acc[kt * 4 + nt][r]);
            m = fmaxf(m, __shfl_xor(m, 16));
            m = fmaxf(m, __shfl_xor(m, 32));
            mx[nt] = m;                     // all lanes: chunk max of column nt*16+m16
            if (lane < 16) atomicMax(&runmaxU[nt * 16 + lane], fenc(m));
        }
#pragma unroll
        for (int nt = 0; nt < 4; ++nt) {
            const int nl = nt * 16 + m16;
            const float thr = fmaxf(fdec(runmaxU[nl]), mx[nt]) - MARGIN;
#pragma unroll
            for (int kt = 0; kt < 4; ++kt)
#pragma unroll
                for (int r = 0; r < 4; ++r) {
                    if (acc[kt * 4 + nt][r] >= thr) {
                        int k = kb + (kt << 4) + q * 4 + r;
                        int pos = atomicAdd(&cnt[nl], 1);
                        if (pos < LCAP) { lstK[nl][pos] = k; lstD[nl][pos] = acc[kt * 4 + nt][r]; }
                    }
                }
        }
        if (s == 3 || s == 9) __syncthreads();   // bound cross-wave staleness
    }

    __syncthreads();   // all pushes + atomicMax done; runmaxU now TRUE global max per n
    if (tid < 64) {
        const int n = nb + tid;
        const int c = cnt[tid];
        if (c > LCAP) {
            candCnt[n] = KK;               // overflow -> exact full-scan fallback
        } else {
            const float thr = fdec(runmaxU[tid]) - MARGIN;
            int kept = 0;
            for (int i = 0; i < c; ++i) {
                if (lstD[tid][i] >= thr) {
                    if (kept < CAND_CAP) candI[(size_t)n * CAND_CAP + kept] = lstK[tid][i];
                    ++kept;
                }
            }
            candCnt[n] = (kept > CAND_CAP) ? KK : kept;
        }
    }
}

// ---------------- Phase 2 (fused): stage + rescore + gather + loss (+finalize) ------
// TAIL FIX (r14 elimination: tail is in-kernel, and the only latency-bound phase is
// the rescore's serial candidate chain: scalar candI read ~300-600cy -> emb row load
// ~600-900cy (emb 8.4MB > 4MB XCD L2) -> 6-shfl butterfly, serial per candidate).
// Changes vs r14: (1) 1024 blocks (16-hw tiles, LDS 17.8 KB) -> 4 blocks/CU =
// 4 waves/SIMD (2x TLP), 4 rows/wave; (2) whole candidate list fetched in ONE
// coalesced load (lane i holds candidate i), k's broadcast via __shfl; (3) emb-row
// loads software-pipelined depth-1 (issue row i+1 before reducing row i).
// Selection math unchanged: d = (zn + enorm[k]) - (p+p), ties -> min k
// (order-invariant). Loss finalized by LAST block via doneCnt (r10/r12/r14-verified;
// __threadfence orders lossAcc add before counter; no spin-wait).
__global__ __launch_bounds__(256)
void k_final(const float* __restrict__ z, const float* __restrict__ emb,
             const float* __restrict__ enorm, const int* __restrict__ candCnt,
             const int* __restrict__ candI, float* __restrict__ out,
             float* __restrict__ idxf, float* __restrict__ lossAcc,
             int* __restrict__ doneCnt, float* __restrict__ outLoss) {
    __shared__ float zl[16][261];     // [hw][c], 16.7 KB
    __shared__ int   kis[16];
    __shared__ float red[256];
    const int bid = blockIdx.x;
    const int b = bid >> 6, hw0 = (bid & 63) << 4;
    const int tid = threadIdx.x;
    const int lane = tid & 63, w = tid >> 6;

    // stage: read float4 along hw (coalesced 64B segments), transpose into zl[hw][c]
#pragma unroll
    for (int p = 0; p < 4; ++p) {
        const int u = p * 256 + tid;
        const int c = u >> 2, j4 = (u & 3) << 2;
        float4 v = *(const float4*)(z + (size_t)b * 262144 + (size_t)c * 1024 + hw0 + j4);
        zl[j4 + 0][c] = v.x; zl[j4 + 1][c] = v.y; zl[j4 + 2][c] = v.z; zl[j4 + 3][c] = v.w;
    }
    __syncthreads();

    // rescore: wave per n, 4 n per wave
#pragma unroll 1
    for (int rr = 0; rr < 4; ++rr) {
        const int j = w * 4 + rr;
        const int n = b * 1024 + hw0 + j;
        const float4 zv = *(const float4*)&zl[j][lane * 4];
        float zn = zv.x * zv.x;
        zn = fmaf(zv.y, zv.y, zn); zn = fmaf(zv.z, zv.z, zn); zn = fmaf(zv.w, zv.w, zn);
#pragma unroll
        for (int off = 1; off < 64; off <<= 1) zn += __shfl_xor(zn, off);
        const int cnt = candCnt[n];
        float bd = __builtin_inff();
        int   bk = 0x7fffffff;
        if (cnt <= CAND_CAP) {
            // one coalesced fetch of the whole candidate list (lane i = candidate i)
            int myk = 0;
            if (lane < cnt) myk = candI[(size_t)n * CAND_CAP + lane];
            if (cnt > 0) {
                int kc = __shfl(myk, 0);
                float4 ev = *(const float4*)(emb + (size_t)kc * CC + lane * 4);
#pragma unroll 1
                for (int i = 0; i < cnt; ++i) {
                    const float4 evc = ev;
                    const int kcur = kc;
                    if (i + 1 < cnt) {      // prefetch next candidate's row
                        kc = __shfl(myk, i + 1);
                        ev = *(const float4*)(emb + (size_t)kc * CC + lane * 4);
                    }
                    float p = zv.x * evc.x;
                    p = fmaf(zv.y, evc.y, p);
                    p = fmaf(zv.z, evc.z, p);
                    p = fmaf(zv.w, evc.w, p);
#pragma unroll
                    for (int off = 1; off < 64; off <<= 1) p += __shfl_xor(p, off);
                    const float d = (zn + enorm[kcur]) - (p + p);
                    if (d < bd || (d == bd && kcur < bk)) { bd = d; bk = kcur; }
                }
            }
        } else {
            // overflow fallback: exact full scan, ascending k keeps min-k
#pragma unroll 1
            for (int k = 0; k < KK; ++k) {
                const float4 ev = *(const float4*)(emb + (size_t)k * CC + lane * 4);
                float p = zv.x * ev.x;
                p = fmaf(zv.y, ev.y, p);
                p = fmaf(zv.z, ev.z, p);
                p = fmaf(zv.w, ev.w, p);
#pragma unroll
                for (int off = 1; off < 64; off <<= 1) p += __shfl_xor(p, off);
                const float d = (zn + enorm[k]) - (p + p);
                if (d < bd) { bd = d; bk = k; }
            }
        }
        if (lane == 0) { idxf[n] = (float)bk; kis[j] = bk; }
    }
    __syncthreads();

    // gather z_q (BCHW, coalesced along hw) + loss partials from the LDS tile
    const int j  = tid & 15;          // hw within tile
    const int cg = tid >> 4;          // c-group of 16
    const int ki0 = kis[j];
    const float* ep = emb + (size_t)ki0 * CC;
    float ls = 0.0f;
#pragma unroll 4
    for (int c = cg * 16; c < cg * 16 + 16; ++c) {
        float e  = ep[c];
        float zv = zl[j][c];
        out[(size_t)b * 262144 + (size_t)c * 1024 + hw0 + j] = e;
        float df = e - zv;
        ls = fmaf(df, df, ls);
    }
    red[tid] = ls;
    __syncthreads();
    for (int s2 = 128; s2 > 0; s2 >>= 1) {
        if (tid < s2) red[tid] += red[tid + s2];
        __syncthreads();
    }
    if (tid == 0) {
        atomicAdd(lossAcc, red[0]);
        __threadfence();                              // order lossAcc add before counter
        int old = atomicAdd(doneCnt, 1);
        if (old == (int)gridDim.x - 1) {              // last block finalizes loss
            float tot = atomicAdd(lossAcc, 0.0f);     // coherent read after all adds
            float m = tot * (1.0f / 4194304.0f);
            outLoss[0] = m + 0.25f * m;
        }
    }
}

extern "C" void kernel_launch(void* const* d_in, const int* in_sizes, int n_in,
                              void* d_out, int out_size, void* d_ws, size_t ws_size,
                              hipStream_t stream) {
    const float* z   = (const float*)d_in[0];
    const float* emb = (const float*)d_in[1];
    float* outf = (float*)d_out;
    float* wsf  = (float*)d_ws;

    float* lossAcc = wsf;
    int*   doneCnt = (int*)(wsf + 1);
    float* enorm   = wsf + WS_ENORM;
    int*   candCnt = (int*)(wsf + WS_CCNT);
    int*   candI   = (int*)(wsf + WS_CIDX);

    // d_out z_q region doubles as scratch: bf16 zb16/ebf until k_cand completes,
    // then k_final overwrites it with z_q.
    unsigned short* zb16 = (unsigned short*)outf;                  // 8 MB
    unsigned short* ebf  = (unsigned short*)(outf + 2097152);      // 4 MB

    k_prep<<<3072, 256, 0, stream>>>(z, emb, zb16, ebf, enorm, lossAcc, doneCnt);
    k_cand<<<256, 512, 0, stream>>>(zb16, ebf, candCnt, candI);
    k_final<<<1024, 256, 0, stream>>>(z, emb, enorm, candCnt, candI,
                                      outf, outf + Z_OUT, lossAcc, doneCnt,
                                      outf + Z_OUT + NPTS);
}

// Round 16
// 255.257 us; speedup vs baseline: 1.0520x; 1.0520x over previous
//
#include <hip/hip_runtime.h>
#include <math.h>

// Problem constants
#define NB   16
#define CC   256
#define NPTS 16384       // 16*32*32
#define KK   8192
#define Z_OUT 4194304    // NPTS*CC
// d_out: [0,Z_OUT) z_q_out (BCHW), [Z_OUT,Z_OUT+NPTS) idx as float, [Z_OUT+NPTS] loss
// d_out scratch: zb16 = bf16[16384][256] at slot 0, ebf = bf16[8192][256] at slot
// 2,097,152 -- both read by k_cand (which writes only idxf, beyond Z_OUT -> no alias);
// k_gather finally overwrites [0, Z_OUT) with z_q BCHW.

// ws layout (floats): lossAcc @0, doneCnt @1, enorm @WS_ENORM. (candCnt/candI GONE --
// candidates never leave k_cand's LDS now.)
#define WS_ENORM 16448
#define LCAP     96                   // per-n LDS candidate list capacity (r8-verified)
#define MARGIN   4.0e-4f              // > 2*eps_bf16 + d-quantum + enorm spread

typedef short v8s __attribute__((ext_vector_type(8)));
typedef float v4f __attribute__((ext_vector_type(4)));

__device__ __forceinline__ void gl_lds16(const void* g, void* l) {
    __builtin_amdgcn_global_load_lds((const __attribute__((address_space(1))) void*)g,
                                     (__attribute__((address_space(3))) void*)l, 16, 0, 0);
}
__device__ __forceinline__ unsigned short f2bf(float f) {   // RNE, finite inputs
    unsigned int u = __float_as_uint(f);
    return (unsigned short)((u + 0x7FFFu + ((u >> 16) & 1u)) >> 16);
}
// monotone float<->uint encoding for atomicMax on floats of any sign
__device__ __forceinline__ unsigned fenc(float f) {
    unsigned u = __float_as_uint(f);
    return (u & 0x80000000u) ? ~u : (u | 0x80000000u);
}
__device__ __forceinline__ float fdec(unsigned m) {
    unsigned u = (m & 0x80000000u) ? (m & 0x7fffffffu) : ~m;
    return __uint_as_float(u);
}

// ---------------- P0 (fused prep): emb->ebf+enorm, z->zb16, zero accumulators -------
// r15-verified. 3072 blocks x 256 thr. Blocks [0,2048): emb fp32 -> ebf bf16 + enorm
// (4 rows/blk, wave/row); block 0 zeros lossAcc+doneCnt. Blocks [2048,3072): z BCHW
// fp32 -> zb16[n][c] bf16 (b2 = bid-2048: x=b2&15, y=(b2>>4)&3, b=b2>>6).
__global__ void k_prep(const float* __restrict__ z, const float* __restrict__ emb,
                       unsigned short* __restrict__ zb16, unsigned short* __restrict__ ebf,
                       float* __restrict__ enorm, float* __restrict__ lossAcc,
                       int* __restrict__ doneCnt) {
    const int bid = blockIdx.x;
    const int tid = threadIdx.x;
    if (bid < 2048) {
        const int w = tid >> 6, lane = tid & 63;
        const int k = bid * 4 + w;
        const int i = k * CC + lane * 4;
        float4 v = *(const float4*)(emb + i);
        *(ushort4*)(ebf + i) = make_ushort4(f2bf(v.x), f2bf(v.y), f2bf(v.z), f2bf(v.w));
        float s = v.x * v.x + v.y * v.y + v.z * v.z + v.w * v.w;
        for (int off = 32; off > 0; off >>= 1) s += __shfl_down(s, off);
        if (lane == 0) enorm[k] = s;
        if (bid == 0 && tid == 0) { lossAcc[0] = 0.0f; doneCnt[0] = 0; }
    } else {
        __shared__ float ts[64][65];
        const int b2 = bid - 2048;
        const int hw0 = (b2 & 15) * 64, c0 = ((b2 >> 4) & 3) * 64, b = b2 >> 6;
#pragma unroll
        for (int p = 0; p < 4; ++p) {
            int u = p * 256 + tid;
            int ci = u >> 4, j4 = (u & 15) << 2;
            float4 v = *(const float4*)(z + (size_t)b * 262144 + (size_t)(c0 + ci) * 1024 + hw0 + j4);
            ts[ci][j4 + 0] = v.x; ts[ci][j4 + 1] = v.y; ts[ci][j4 + 2] = v.z; ts[ci][j4 + 3] = v.w;
        }
        __syncthreads();
#pragma unroll
        for (int p = 0; p < 4; ++p) {
            int u = p * 256 + tid;
            int hj = u >> 4, i4 = (u & 15) << 2;
            ushort4 o = make_ushort4(f2bf(ts[i4 + 0][hj]), f2bf(ts[i4 + 1][hj]),
                                     f2bf(ts[i4 + 2][hj]), f2bf(ts[i4 + 3][hj]));
            *(ushort4*)(zb16 + (size_t)(b * 1024 + hw0 + hj) * 256 + c0 + i4) = o;
        }
    }
}

// ---------------- Phase 1: MFMA candidate sweep + FUSED exact rescore ---------------
// Sweep = r8-verified structure byte-for-byte (145 us): 256 blocks x 512 thr (8
// waves). Block = 64 n; B z-tile staged ONCE in LDS; wave w sweeps chunks ci=s*8+w;
// A depth-3 prefetch ring, B LDS ping-pong; progressive threshold max(shared runmax,
// own chunk max) - MARGIN -> LDS lists; runmaxU converges to the TRUE global max.
// NEW (r15 tail analysis: k_final's stage+rescore wall >> its traffic roofline, and
// everything it needs is already in this block's LDS at sweep end): the exact fp32
// rescore is fused here. After the sweep: stage zl[64][257] fp32 from z BCHW
// (coalesced float4 along hw), then wave-per-n (8 n/wave): wave-parallel final
// filter (lane i holds list entry i, ballot-compact vs thr), depth-1-pipelined fp32
// emb-row loads (r15-verified chain), d = (zn + enorm[k]) - (p+p), ties -> min k.
// Writes idxf only (beyond Z_OUT -> no alias with zb16/ebf scratch). Fallback: cnt
// > 64 -> exact full 8192-scan in-block (never hit in r8/r14/r15 practice).
// LDS 144.8 KB -> 1 block/CU (unchanged: 82.4 KB already forced 1 block/CU).
// mfma_f32_16x16x32_bf16: A[m=lane&15][c=(lane>>4)*8+j]; B[c][n=lane&15];
// D: col(n)=lane&15, row(k)=(lane>>4)*4+reg.
__global__ __launch_bounds__(512, 2)
void k_cand(const unsigned short* __restrict__ zb16, const unsigned short* __restrict__ ebf,
            const float* __restrict__ z, const float* __restrict__ emb,
            const float* __restrict__ enorm, float* __restrict__ idxf) {
    __shared__ short    Bs[8][4][512];      // 32 KB  [cchunk][ntile][lane*8]
    __shared__ unsigned runmaxU[64];        // ordered-uint running max per n
    __shared__ int      cnt[64];
    __shared__ int      lstK[64][LCAP];     // 24 KB
    __shared__ float    lstD[64][LCAP];     // 24 KB
    __shared__ float    zl[64][257];        // 64.25 KB fp32 z tile (rescore phase)

    const int tid  = threadIdx.x;
    const int lane = tid & 63;
    const int w    = tid >> 6;              // 0..7
    const int nb   = blockIdx.x << 6;
    const int m16  = lane & 15, q = lane >> 4;

    if (tid < 64) { runmaxU[tid] = 0x007FFFFFu; /* fenc(-inf) */ cnt[tid] = 0; }

    // stage B-tile once: 32 (cc,nt) fragments x 64 lanes x 16B; 4 per wave
#pragma unroll
    for (int p = 0; p < 4; ++p) {
        const int g8 = p * 8 + w;          // 0..31, wave-uniform
        const int cc = g8 >> 2, nt = g8 & 3;
        const unsigned short* g = zb16 + (size_t)(nb + nt * 16 + m16) * 256 + cc * 32 + q * 8;
        gl_lds16(g, &Bs[cc][nt][lane * 8]);
    }

    auto loadA = [&](v8s (&a)[4], int kbr, int cc) {
#pragma unroll
        for (int kt = 0; kt < 4; ++kt)
            a[kt] = *(const v8s*)(ebf + (size_t)(kbr + (kt << 4) + m16) * 256 + (cc << 5) + q * 8);
    };
    auto loadB = [&](v8s (&b)[4], int cc) {
#pragma unroll
        for (int nt = 0; nt < 4; ++nt) b[nt] = *(const v8s*)&Bs[cc][nt][lane * 8];
    };

    v8s aR[4][4];            // A ring (static indices only -- cc fully unrolled)
    v8s bP[4], bN[4];

    // prologue: seed ring with (s=0, cc=0,1,2); registers only, safe pre-barrier
    const int kb0 = w << 6;                // s=0 -> ci=w
    loadA(aR[0], kb0, 0);
    loadA(aR[1], kb0, 1);
    loadA(aR[2], kb0, 2);
    __syncthreads();       // Bs staged + runmaxU/cnt init visible (drains vmcnt once)
    loadB(bP, 0);

#pragma unroll 1
    for (int s = 0; s < 16; ++s) {
        const int kb  = ((s << 3) + w) << 6;           // this wave's chunk (64 k)
        const int kbn = (s < 15) ? kb + 512 : kb;      // next s's chunk (ci+8)
        v4f acc[16];
#pragma unroll
        for (int i = 0; i < 16; ++i) acc[i] = (v4f){0.f, 0.f, 0.f, 0.f};

#pragma unroll
        for (int cc = 0; cc < 8; ++cc) {
            if ((cc & 1) == 0) loadB(bN, (cc + 1) & 7);
            else               loadB(bP, (cc + 1) & 7);
            {
                const int tcc = cc + 3;
                if (tcc < 8) loadA(aR[tcc & 3], kb,  tcc);
                else         loadA(aR[tcc & 3], kbn, tcc - 8);
            }
#pragma unroll
            for (int kt = 0; kt < 4; ++kt)
#pragma unroll
                for (int nt = 0; nt < 4; ++nt)
                    acc[kt * 4 + nt] = __builtin_amdgcn_mfma_f32_16x16x32_bf16(
                        aR[cc & 3][kt], ((cc & 1) ? bN[nt] : bP[nt]),
                        acc[kt * 4 + nt], 0, 0, 0);
        }

        // chunk epilogue: own-chunk max per n-column, merge into shared runmax, push.
        float mx[4];
#pragma unroll
        for (int nt = 0; nt < 4; ++nt) {
            float m = acc[0 * 4 + nt][0];
#pragma unroll
            for (int kt = 0; kt < 4; ++kt)
#pragma unroll
                for (int r = 0; r < 4; ++r) m = fmaxf(m, acc[kt * 4 + nt][r]);
            m = fmaxf(m, __shfl_xor(m, 16));
            m = fmaxf(m, __shfl_xor(m, 32));
            mx[nt] = m;                     // all lanes: chunk max of column nt*16+m16
            if (lane < 16) atomicMax(&runmaxU[nt * 16 + lane], fenc(m));
        }
#pragma unroll
        for (int nt = 0; nt < 4; ++nt) {
            const int nl = nt * 16 + m16;
            const float thr = fmaxf(fdec(runmaxU[nl]), mx[nt]) - MARGIN;
#pragma unroll
            for (int kt = 0; kt < 4; ++kt)
#pragma unroll
                for (int r = 0; r < 4; ++r) {
                    if (acc[kt * 4 + nt][r] >= thr) {
                        int k = kb + (kt << 4) + q * 4 + r;
                        int pos = atomicAdd(&cnt[nl], 1);
                        if (pos < LCAP) { lstK[nl][pos] = k; lstD[nl][pos] = acc[kt * 4 + nt][r]; }
                    }
                }
        }
        if (s == 3 || s == 9) __syncthreads();   // bound cross-wave staleness
    }

    __syncthreads();   // all pushes + atomicMax done; runmaxU now TRUE global max per n

    // ---- fused exact rescore (replaces k_final's stage+rescore) ----
    // stage zl[64][257] fp32 from z BCHW: coalesced float4 along hw; pad 257 keeps
    // writes ~2-way and the b128 row-reads conflict-light.
    {
        const int b = nb >> 10, hw0 = nb & 1023;
#pragma unroll
        for (int p = 0; p < 8; ++p) {
            const int u = p * 512 + tid;
            const int c = u >> 4, j4 = (u & 15) << 2;
            float4 v = *(const float4*)(z + (size_t)b * 262144 + (size_t)c * 1024 + hw0 + j4);
            zl[j4 + 0][c] = v.x; zl[j4 + 1][c] = v.y; zl[j4 + 2][c] = v.z; zl[j4 + 3][c] = v.w;
        }
    }
    __syncthreads();

    // wave per n, 8 n per wave: wave-parallel filter + pipelined fp32 emb rows
#pragma unroll 1
    for (int rr = 0; rr < 8; ++rr) {
        const int nl = w * 8 + rr;
        const int n  = nb + nl;
        const float4 zv = *(const float4*)&zl[nl][lane * 4];
        float zn = zv.x * zv.x;
        zn = fmaf(zv.y, zv.y, zn); zn = fmaf(zv.z, zv.z, zn); zn = fmaf(zv.w, zv.w, zn);
#pragma unroll
        for (int off = 1; off < 64; off <<= 1) zn += __shfl_xor(zn, off);
        const int cl = cnt[nl];
        float bd = __builtin_inff();
        int   bk = 0x7fffffff;
        if (cl <= 64) {   // fast path: whole list fits one wave (typ. cl ~ 5-25)
            int  ki = 0;
            bool pass = false;
            if (lane < cl) {
                ki = lstK[nl][lane];
                pass = (lstD[nl][lane] >= fdec(runmaxU[nl]) - MARGIN);
            }
            unsigned long long mask = __ballot(pass);
            int kc = -1;
            float4 ev;
            if (mask) {
                const int j0 = __ffsll(mask) - 1; mask &= mask - 1;
                kc = __shfl(ki, j0);
                ev = *(const float4*)(emb + (size_t)kc * CC + lane * 4);
            }
            while (kc >= 0) {
                const int    kcur = kc;
                const float4 evc  = ev;
                if (mask) {                          // prefetch next candidate's row
                    const int jn = __ffsll(mask) - 1; mask &= mask - 1;
                    kc = __shfl(ki, jn);
                    ev = *(const float4*)(emb + (size_t)kc * CC + lane * 4);
                } else kc = -1;
                float p = zv.x * evc.x;
                p = fmaf(zv.y, evc.y, p);
                p = fmaf(zv.z, evc.z, p);
                p = fmaf(zv.w, evc.w, p);
#pragma unroll
                for (int off = 1; off < 64; off <<= 1) p += __shfl_xor(p, off);
                const float d = (zn + enorm[kcur]) - (p + p);
                if (d < bd || (d == bd && kcur < bk)) { bd = d; bk = kcur; }
            }
        } else {
            // overflow fallback: exact full scan, ascending k keeps min-k
#pragma unroll 1
            for (int k = 0; k < KK; ++k) {
                const float4 ev = *(const float4*)(emb + (size_t)k * CC + lane * 4);
                float p = zv.x * ev.x;
                p = fmaf(zv.y, ev.y, p);
                p = fmaf(zv.z, ev.z, p);
                p = fmaf(zv.w, ev.w, p);
#pragma unroll
                for (int off = 1; off < 64; off <<= 1) p += __shfl_xor(p, off);
                const float d = (zn + enorm[k]) - (p + p);
                if (d < bd) { bd = d; bk = k; }
            }
        }
        if (lane == 0) idxf[n] = (float)bk;
    }
}

// ---------------- gather z_q (BCHW) + loss partials (+finalize) ---------------------
// r0-verified gather (512 blocks x 256 thr, block = one h-row of 32 w, all c) +
// r10/r12/r14-verified last-block loss finalize (device-scope atomics; __threadfence
// orders lossAcc add before counter; no spin-wait -> no deadlock).
__global__ __launch_bounds__(256)
void k_gather(const float* __restrict__ z, const float* __restrict__ emb,
              const float* __restrict__ idxf, float* __restrict__ out,
              float* __restrict__ lossAcc, int* __restrict__ doneCnt,
              float* __restrict__ outLoss) {
    __shared__ float red[256];
    const int bid = blockIdx.x;
    const int b = bid >> 5, h = bid & 31;
    const int t = threadIdx.x;
    const int w_ = t & 31, cg = t >> 5;
    const int n = b * 1024 + h * 32 + w_;
    const int ki = (int)idxf[n];
    const float* ep = emb + (size_t)ki * CC;
    const size_t base = (size_t)b * 262144 + h * 32 + w_;
    float ls = 0.0f;
#pragma unroll 4
    for (int c = cg; c < CC; c += 8) {
        float e = ep[c];
        size_t a = base + (size_t)c * 1024;
        float zv = z[a];
        out[a] = e;
        float df = e - zv;
        ls = fmaf(df, df, ls);
    }
    red[t] = ls;
    __syncthreads();
    for (int s = 128; s > 0; s >>= 1) {
        if (t < s) red[t] += red[t + s];
        __syncthreads();
    }
    if (t == 0) {
        atomicAdd(lossAcc, red[0]);
        __threadfence();                              // order lossAcc add before counter
        int old = atomicAdd(doneCnt, 1);
        if (old == (int)gridDim.x - 1) {              // last block finalizes loss
            float tot = atomicAdd(lossAcc, 0.0f);     // coherent read after all adds
            float m = tot * (1.0f / 4194304.0f);
            outLoss[0] = m + 0.25f * m;
        }
    }
}

extern "C" void kernel_launch(void* const* d_in, const int* in_sizes, int n_in,
                              void* d_out, int out_size, void* d_ws, size_t ws_size,
                              hipStream_t stream) {
    const float* z   = (const float*)d_in[0];
    const float* emb = (const float*)d_in[1];
    float* outf = (float*)d_out;
    float* wsf  = (float*)d_ws;

    float* lossAcc = wsf;
    int*   doneCnt = (int*)(wsf + 1);
    float* enorm   = wsf + WS_ENORM;

    // d_out z_q region doubles as scratch: bf16 zb16/ebf until k_cand completes
    // (k_cand writes only idxf, beyond Z_OUT), then k_gather overwrites with z_q.
    unsigned short* zb16 = (unsigned short*)outf;                  // 8 MB
    unsigned short* ebf  = (unsigned short*)(outf + 2097152);      // 4 MB

    k_prep<<<3072, 256, 0, stream>>>(z, emb, zb16, ebf, enorm, lossAcc, doneCnt);
    k_cand<<<256, 512, 0, stream>>>(zb16, ebf, z, emb, enorm, outf + Z_OUT);
    k_gather<<<512, 256, 0, stream>>>(z, emb, outf + Z_OUT, outf,
                                      lossAcc, doneCnt, outf + Z_OUT + NPTS);
}

// Round 17
// 237.148 us; speedup vs baseline: 1.1324x; 1.0764x over previous
//
#include <hip/hip_runtime.h>
#include <math.h>

// Problem constants
#define NB   16
#define CC   256
#define NPTS 16384       // 16*32*32
#define KK   8192
#define Z_OUT 4194304    // NPTS*CC
// d_out: [0,Z_OUT) z_q_out (BCHW), [Z_OUT,Z_OUT+NPTS) idx as float, [Z_OUT+NPTS] loss
// SCRATCH NOW LIVES IN d_ws (not d_out): ebf = bf16[8192][256] at ws float offset
// WS_EBF. d_out is written only as true output -> no aliasing, enabling full fusion.

// ws layout (floats): lossAcc @0, doneCnt @1, enorm @WS_ENORM, ebf @WS_EBF.
// Total ws use: 32768 + 1048576 floats ~ 4.3 MB (rounds 0-8 used ~17 MB -> fits).
#define WS_ENORM 16448
#define WS_EBF   32768
#define LCAP     96                   // per-n LDS candidate list capacity (r8-verified)
#define MARGIN   4.0e-4f              // > 2*eps_bf16 + d-quantum + enorm spread

typedef short v8s __attribute__((ext_vector_type(8)));
typedef float v4f __attribute__((ext_vector_type(4)));

__device__ __forceinline__ unsigned short f2bf(float f) {   // RNE, finite inputs
    unsigned int u = __float_as_uint(f);
    return (unsigned short)((u + 0x7FFFu + ((u >> 16) & 1u)) >> 16);
}
// monotone float<->uint encoding for atomicMax on floats of any sign
__device__ __forceinline__ unsigned fenc(float f) {
    unsigned u = __float_as_uint(f);
    return (u & 0x80000000u) ? ~u : (u | 0x80000000u);
}
__device__ __forceinline__ float fdec(unsigned m) {
    unsigned u = (m & 0x80000000u) ? (m & 0x7fffffffu) : ~m;
    return __uint_as_float(u);
}

// ---------------- P0: emb fp32 -> ebf bf16 + enorm; zero accumulators ---------------
// 2048 blocks x 256 thr: 4 rows/block, wave/row (r15-verified branch, now standalone;
// the z->zb16 transpose pass is GONE -- k_cand builds its bf16 z fragments from its
// own fp32 LDS tile, bit-identical values via the same f2bf).
__global__ void k_prep(const float* __restrict__ emb, unsigned short* __restrict__ ebf,
                       float* __restrict__ enorm, float* __restrict__ lossAcc,
                       int* __restrict__ doneCnt) {
    const int w = threadIdx.x >> 6, lane = threadIdx.x & 63;
    const int k = blockIdx.x * 4 + w;
    const int i = k * CC + lane * 4;
    float4 v = *(const float4*)(emb + i);
    *(ushort4*)(ebf + i) = make_ushort4(f2bf(v.x), f2bf(v.y), f2bf(v.z), f2bf(v.w));
    float s = v.x * v.x + v.y * v.y + v.z * v.z + v.w * v.w;
    for (int off = 32; off > 0; off >>= 1) s += __shfl_down(s, off);
    if (lane == 0) enorm[k] = s;
    if (blockIdx.x == 0 && threadIdx.x == 0) { lossAcc[0] = 0.0f; doneCnt[0] = 0; }
}

// ---------------- Phase 1 (fully fused): sweep + rescore + gather + loss ------------
// Sweep = r8/r16-verified structure: 256 blocks x 512 thr (8 waves), block = 64 n,
// wave w sweeps chunks ci=s*8+w; A depth-3 ring from ebf, B ping-pong from LDS Bs;
// progressive threshold max(shared runmax, own chunk max) - MARGIN -> LDS lists;
// runmaxU converges to the TRUE global max; exact filter + fp32 rescore (r16).
// NEW vs r16: (1) zl fp32 z-tile staged at kernel START; Bs fragments built from zl
// in-LDS (f2bf of the same fp32 values as the old zb16 path -> bit-identical sweep);
// (2) scratch in d_ws -> out is alias-free -> gather + loss fused at the end: after
// rescore, each wave re-reads its winner emb rows (L2-hot), computes loss partials
// vs zl (the exact fp32 z), overwrites zl rows with e, then the block writes out
// BCHW coalesced from zl and last block finalizes loss (r10-verified doneCnt).
// LDS ~145 KB -> 1 block/CU (unchanged). Spill tripwire: WRITE_SIZE >> 17 MB.
// mfma_f32_16x16x32_bf16: A[m=lane&15][c=(lane>>4)*8+j]; B[c][n=lane&15];
// D: col(n)=lane&15, row(k)=(lane>>4)*4+reg.
__global__ __launch_bounds__(512, 2)
void k_cand(const unsigned short* __restrict__ ebf, const float* __restrict__ z,
            const float* __restrict__ emb, const float* __restrict__ enorm,
            float* __restrict__ out, float* __restrict__ idxf,
            float* __restrict__ lossAcc, int* __restrict__ doneCnt,
            float* __restrict__ outLoss) {
    __shared__ short    Bs[8][4][512];      // 32 KB  [cchunk][ntile][lane*8]
    __shared__ unsigned runmaxU[64];        // ordered-uint running max per n
    __shared__ int      cnt[64];
    __shared__ int      lstK[64][LCAP];     // 24 KB
    __shared__ float    lstD[64][LCAP];     // 24 KB
    __shared__ float    zl[64][257];        // 64.25 KB fp32 z tile (whole kernel)
    __shared__ float    lossP[8];

    const int tid  = threadIdx.x;
    const int lane = tid & 63;
    const int w    = tid >> 6;              // 0..7
    const int nb   = blockIdx.x << 6;
    const int b    = nb >> 10, hw0 = nb & 1023;
    const int m16  = lane & 15, q = lane >> 4;

    if (tid < 64) { runmaxU[tid] = 0x007FFFFFu; /* fenc(-inf) */ cnt[tid] = 0; }

    // stage zl[64][257] fp32 from z BCHW: coalesced float4 along hw (r16-verified)
#pragma unroll
    for (int p = 0; p < 8; ++p) {
        const int u = p * 512 + tid;
        const int c = u >> 4, j4 = (u & 15) << 2;
        float4 v = *(const float4*)(z + (size_t)b * 262144 + (size_t)c * 1024 + hw0 + j4);
        zl[j4 + 0][c] = v.x; zl[j4 + 1][c] = v.y; zl[j4 + 2][c] = v.z; zl[j4 + 3][c] = v.w;
    }
    __syncthreads();

    // build Bs fragments from zl (replaces the zb16 global pass; identical values:
    // Bs[cc][nt][lane*8+e] = f2bf(z[n=nt*16+m16][c=cc*32+q*8+e]))
#pragma unroll
    for (int p = 0; p < 4; ++p) {
        const int g8 = p * 8 + w;          // 0..31, wave-uniform
        const int cc = g8 >> 2, nt = g8 & 3;
        const int row = nt * 16 + m16, col = cc * 32 + q * 8;
        float4 va = *(const float4*)&zl[row][col];
        float4 vb = *(const float4*)&zl[row][col + 4];
        ushort4* dst = (ushort4*)&Bs[cc][nt][lane * 8];
        dst[0] = make_ushort4(f2bf(va.x), f2bf(va.y), f2bf(va.z), f2bf(va.w));
        dst[1] = make_ushort4(f2bf(vb.x), f2bf(vb.y), f2bf(vb.z), f2bf(vb.w));
    }

    auto loadA = [&](v8s (&a)[4], int kbr, int cc) {
#pragma unroll
        for (int kt = 0; kt < 4; ++kt)
            a[kt] = *(const v8s*)(ebf + (size_t)(kbr + (kt << 4) + m16) * 256 + (cc << 5) + q * 8);
    };
    auto loadB = [&](v8s (&bfrag)[4], int cc) {
#pragma unroll
        for (int nt = 0; nt < 4; ++nt) bfrag[nt] = *(const v8s*)&Bs[cc][nt][lane * 8];
    };

    v8s aR[4][4];            // A ring (static indices only -- cc fully unrolled)
    v8s bP[4], bN[4];

    // prologue: seed ring with (s=0, cc=0,1,2); registers only, safe pre-barrier
    const int kb0 = w << 6;                // s=0 -> ci=w
    loadA(aR[0], kb0, 0);
    loadA(aR[1], kb0, 1);
    loadA(aR[2], kb0, 2);
    __syncthreads();       // Bs built + runmaxU/cnt init visible
    loadB(bP, 0);

#pragma unroll 1
    for (int s = 0; s < 16; ++s) {
        const int kb  = ((s << 3) + w) << 6;           // this wave's chunk (64 k)
        const int kbn = (s < 15) ? kb + 512 : kb;      // next s's chunk (ci+8)
        v4f acc[16];
#pragma unroll
        for (int i = 0; i < 16; ++i) acc[i] = (v4f){0.f, 0.f, 0.f, 0.f};

#pragma unroll
        for (int cc = 0; cc < 8; ++cc) {
            if ((cc & 1) == 0) loadB(bN, (cc + 1) & 7);
            else               loadB(bP, (cc + 1) & 7);
            {
                const int tcc = cc + 3;
                if (tcc < 8) loadA(aR[tcc & 3], kb,  tcc);
                else         loadA(aR[tcc & 3], kbn, tcc - 8);
            }
#pragma unroll
            for (int kt = 0; kt < 4; ++kt)
#pragma unroll
                for (int nt = 0; nt < 4; ++nt)
                    acc[kt * 4 + nt] = __builtin_amdgcn_mfma_f32_16x16x32_bf16(
                        aR[cc & 3][kt], ((cc & 1) ? bN[nt] : bP[nt]),
                        acc[kt * 4 + nt], 0, 0, 0);
        }

        // chunk epilogue: own-chunk max per n-column, merge into shared runmax, push.
        float mx[4];
#pragma unroll
        for (int nt = 0; nt < 4; ++nt) {
            float m = acc[0 * 4 + nt][0];
#pragma unroll
            for (int kt = 0; kt < 4; ++kt)
#pragma unroll
                for (int r = 0; r < 4; ++r) m = fmaxf(m, acc[kt * 4 + nt][r]);
            m = fmaxf(m, __shfl_xor(m, 16));
            m = fmaxf(m, __shfl_xor(m, 32));
            mx[nt] = m;                     // all lanes: chunk max of column nt*16+m16
            if (lane < 16) atomicMax(&runmaxU[nt * 16 + lane], fenc(m));
        }
#pragma unroll
        for (int nt = 0; nt < 4; ++nt) {
            const int nl = nt * 16 + m16;
            const float thr = fmaxf(fdec(runmaxU[nl]), mx[nt]) - MARGIN;
#pragma unroll
            for (int kt = 0; kt < 4; ++kt)
#pragma unroll
                for (int r = 0; r < 4; ++r) {
                    if (acc[kt * 4 + nt][r] >= thr) {
                        int k = kb + (kt << 4) + q * 4 + r;
                        int pos = atomicAdd(&cnt[nl], 1);
                        if (pos < LCAP) { lstK[nl][pos] = k; lstD[nl][pos] = acc[kt * 4 + nt][r]; }
                    }
                }
        }
        if (s == 3 || s == 9) __syncthreads();   // bound cross-wave staleness
    }

    __syncthreads();   // all pushes + atomicMax done; runmaxU now TRUE global max per n

    // ---- fused exact rescore + loss partial + e into zl (wave per n, 8 n/wave) ----
    float wls = 0.0f;
#pragma unroll 1
    for (int rr = 0; rr < 8; ++rr) {
        const int nl = w * 8 + rr;
        const int n  = nb + nl;
        const float4 zv = *(const float4*)&zl[nl][lane * 4];
        float zn = zv.x * zv.x;
        zn = fmaf(zv.y, zv.y, zn); zn = fmaf(zv.z, zv.z, zn); zn = fmaf(zv.w, zv.w, zn);
#pragma unroll
        for (int off = 1; off < 64; off <<= 1) zn += __shfl_xor(zn, off);
        const int cl = cnt[nl];
        float bd = __builtin_inff();
        int   bk = 0x7fffffff;
        if (cl <= 64) {   // fast path: whole list fits one wave (typ. cl ~ 5-25)
            int  ki = 0;
            bool pass = false;
            if (lane < cl) {
                ki = lstK[nl][lane];
                pass = (lstD[nl][lane] >= fdec(runmaxU[nl]) - MARGIN);
            }
            unsigned long long mask = __ballot(pass);
            int kc = -1;
            float4 ev;
            if (mask) {
                const int j0 = __ffsll(mask) - 1; mask &= mask - 1;
                kc = __shfl(ki, j0);
                ev = *(const float4*)(emb + (size_t)kc * CC + lane * 4);
            }
            while (kc >= 0) {
                const int    kcur = kc;
                const float4 evc  = ev;
                if (mask) {                          // prefetch next candidate's row
                    const int jn = __ffsll(mask) - 1; mask &= mask - 1;
                    kc = __shfl(ki, jn);
                    ev = *(const float4*)(emb + (size_t)kc * CC + lane * 4);
                } else kc = -1;
                float p = zv.x * evc.x;
                p = fmaf(zv.y, evc.y, p);
                p = fmaf(zv.z, evc.z, p);
                p = fmaf(zv.w, evc.w, p);
#pragma unroll
                for (int off = 1; off < 64; off <<= 1) p += __shfl_xor(p, off);
                const float d = (zn + enorm[kcur]) - (p + p);
                if (d < bd || (d == bd && kcur < bk)) { bd = d; bk = kcur; }
            }
        } else {
            // overflow fallback: exact full scan, ascending k keeps min-k
#pragma unroll 1
            for (int k = 0; k < KK; ++k) {
                const float4 ev = *(const float4*)(emb + (size_t)k * CC + lane * 4);
                float p = zv.x * ev.x;
                p = fmaf(zv.y, ev.y, p);
                p = fmaf(zv.z, ev.z, p);
                p = fmaf(zv.w, ev.w, p);
#pragma unroll
                for (int off = 1; off < 64; off <<= 1) p += __shfl_xor(p, off);
                const float d = (zn + enorm[k]) - (p + p);
                if (d < bd) { bd = d; bk = k; }
            }
        }
        // bk is wave-uniform (d was butterfly-reduced). Winner row -> loss + zl.
        if (lane == 0) idxf[n] = (float)bk;
        const float4 ew = *(const float4*)(emb + (size_t)bk * CC + lane * 4);  // L2-hot
        float dx = ew.x - zv.x, dy = ew.y - zv.y, dz2 = ew.z - zv.z, dw = ew.w - zv.w;
        float ls = dx * dx;
        ls = fmaf(dy, dy, ls); ls = fmaf(dz2, dz2, ls); ls = fmaf(dw, dw, ls);
#pragma unroll
        for (int off = 1; off < 64; off <<= 1) ls += __shfl_xor(ls, off);
        wls += ls;                                   // uniform across lanes
        // overwrite zl row with the quantized vector (this wave owns this row)
        zl[nl][lane * 4 + 0] = ew.x; zl[nl][lane * 4 + 1] = ew.y;
        zl[nl][lane * 4 + 2] = ew.z; zl[nl][lane * 4 + 3] = ew.w;
    }
    if (lane == 0) lossP[w] = wls;
    __syncthreads();

    // ---- out-write: z_q BCHW coalesced from zl (float4 across 4 hw rows) ----
#pragma unroll
    for (int p = 0; p < 8; ++p) {
        const int u = p * 512 + tid;
        const int c = u >> 4, j4 = (u & 15) << 2;
        float4 o = make_float4(zl[j4 + 0][c], zl[j4 + 1][c], zl[j4 + 2][c], zl[j4 + 3][c]);
        *(float4*)(out + (size_t)b * 262144 + (size_t)c * 1024 + hw0 + j4) = o;
    }

    if (tid == 0) {
        float bl = lossP[0];
#pragma unroll
        for (int i = 1; i < 8; ++i) bl += lossP[i];
        atomicAdd(lossAcc, bl);
        __threadfence();                              // order lossAcc add before counter
        int old = atomicAdd(doneCnt, 1);
        if (old == (int)gridDim.x - 1) {              // last block finalizes loss
            float tot = atomicAdd(lossAcc, 0.0f);     // coherent read after all adds
            float m = tot * (1.0f / 4194304.0f);
            outLoss[0] = m + 0.25f * m;
        }
    }
}

extern "C" void kernel_launch(void* const* d_in, const int* in_sizes, int n_in,
                              void* d_out, int out_size, void* d_ws, size_t ws_size,
                              hipStream_t stream) {
    const float* z   = (const float*)d_in[0];
    const float* emb = (const float*)d_in[1];
    float* outf = (float*)d_out;
    float* wsf  = (float*)d_ws;

    float* lossAcc = wsf;
    int*   doneCnt = (int*)(wsf + 1);
    float* enorm   = wsf + WS_ENORM;
    unsigned short* ebf = (unsigned short*)(wsf + WS_EBF);   // 4 MB scratch in ws

    k_prep<<<2048, 256, 0, stream>>>(emb, ebf, enorm, lossAcc, doneCnt);
    k_cand<<<256, 512, 0, stream>>>(ebf, z, emb, enorm,
                                    outf, outf + Z_OUT, lossAcc, doneCnt,
                                    outf + Z_OUT + NPTS);
}